// Round 7
// baseline (918.919 us; speedup 1.0000x reference)
//
#include <hip/hip_runtime.h>

#define RN      128   // REAL
#define START_T 126
#define END_T   127
#define GS      32    // X staging group size

typedef short v8s __attribute__((ext_vector_type(8)));   // 8 x bf16 MFMA A/B frag
typedef float v4f __attribute__((ext_vector_type(4)));   // 4 x f32 MFMA C/D frag

// bf16 round-to-nearest-even (used once, for E)
__device__ __forceinline__ unsigned short f2bf(float f) {
    unsigned u = __float_as_uint(f);
    u += 0x7fffu + ((u >> 16) & 1u);
    return (unsigned short)(u >> 16);
}
__device__ __forceinline__ float bf2f(unsigned short s) { return __uint_as_float(((unsigned)s) << 16); }

// ONE WAVE per block: no __syncthreads anywhere; LDS ordering is intra-wave lgkmcnt.
__global__ __launch_bounds__(64, 1)
void crf_nll_kernel(const float* __restrict__ X,
                    const int*   __restrict__ y,
                    const float* __restrict__ trans,
                    float* __restrict__ out, int L)
{
    const int b    = blockIdx.x;
    const int lane = threadIdx.x;   // 0..63
    const int col  = lane & 15;
    const int quad = lane >> 4;

    __shared__ __align__(16) unsigned short pbuf[RN];   // bf16 scaled probs (single buffer: reads of
                                                        // step t complete before its writes issue)
    __shared__ __align__(16) float xst[2][GS][RN];      // exp(X) staged GS steps at a time

    const float* Xb = X + (size_t)b * (size_t)L * RN;
    const int*   yb = y + (size_t)b * L;

    // ---------------- gold path score ----------------
    float g = 0.f;
    for (int t = lane; t < L; t += 64) {
        int yt = yb[t];
        int yp = t ? yb[t - 1] : START_T;
        g += trans[yt * RN + yp] + Xb[(size_t)t * RN + yt];
    }
    #pragma unroll
    for (int off = 1; off < 64; off <<= 1) g += __shfl_xor(g, off, 64);
    const float goldv = g + trans[END_T * RN + yb[L - 1]];

    // ---------------- init p = onehot(START) in bf16 ----------------
    pbuf[lane]      = (lane      == START_T) ? (unsigned short)0x3F80 : (unsigned short)0;
    pbuf[lane + 64] = (lane + 64 == START_T) ? (unsigned short)0x3F80 : (unsigned short)0;

    // ---------------- X staging (per-wave, no barrier) ----------------
    const size_t lim = (size_t)L * RN;
    auto stage = [&](int t0, int buf) {
        const size_t base = (size_t)t0 * RN;
        float* dst = &xst[buf][0][0];
        #pragma unroll
        for (int c = 0; c < (GS * RN) / (64 * 4); ++c) {   // 16 float4 per lane
            const int f = 4 * lane + 256 * c;
            float4 v;
            if (base + f + 3 < lim) {
                v = *(const float4*)(Xb + base + f);
            } else {
                float* pv = (float*)&v;
                #pragma unroll
                for (int j = 0; j < 4; ++j) { size_t ix = base + f + j; if (ix >= lim) ix = lim - 1; pv[j] = Xb[ix]; }
            }
            float4 e; e.x = __expf(v.x); e.y = __expf(v.y); e.z = __expf(v.z); e.w = __expf(v.w);
            *(float4*)(dst + f) = e;
        }
    };
    stage(0, 0);

    // ---------------- E = exp(trans) as bf16 A-frags, fully register-resident ----------------
    // Tile T: rows 16T..16T+15. A[m=16T+col][k=32c+8quad+j]. Masked (-1e4) -> exactly 0.
    v8s Ef[8][4];
    #pragma unroll
    for (int T = 0; T < 8; ++T) {
        #pragma unroll
        for (int c = 0; c < 4; ++c) {
            const float* tr = trans + (16 * T + col) * RN + 32 * c + 8 * quad;
            v8s v;
            #pragma unroll
            for (int j = 0; j < 8; ++j) v[j] = (short)f2bf(__expf(tr[j]));
            Ef[T][c] = v;
        }
    }

    int lsc2  = 0;        // exact integer log2-scale accumulator
    int mbits = 0x3F80;   // bf16 bits of last measured max, exponent-masked (power of two)
    const int tq = 4 * quad;

    // phase is always a literal -> branches constant-fold after inlining
    auto step = [&](int phase, const float* __restrict__ es) {
        const v8s* PB = (const v8s*)pbuf;
        v8s B0 = PB[0 + quad], B1 = PB[4 + quad], B2 = PB[8 + quad], B3 = PB[12 + quad];

        if (phase == 1) {   // measure max(p) (bf16 bits; p>=0 so int order == float order)
            int mi = 0;
            #pragma unroll
            for (int j = 0; j < 8; ++j) {
                int u0 = (unsigned short)B0[j], u1 = (unsigned short)B1[j];
                int u2 = (unsigned short)B2[j], u3 = (unsigned short)B3[j];
                int m01 = u0 > u1 ? u0 : u1, m23 = u2 > u3 ? u2 : u3;
                int mm  = m01 > m23 ? m01 : m23;
                mi = mm > mi ? mm : mi;
            }
            int d = __shfl_xor(mi, 16, 64); mi = d > mi ? d : mi;   // cross-quad
            d     = __shfl_xor(mi, 32, 64); mi = d > mi ? d : mi;
            mbits = mi & 0x7F80;   // power-of-two floor of the max
        }
        float invv = 1.0f;
        if (phase == 2) {   // apply: exact exponent-arithmetic reciprocal + integer log2
            invv = __uint_as_float(0x7F000000u - (((unsigned)mbits) << 16));
            lsc2 += (mbits >> 7) - 127;
        }

        // 32 MFMAs: 8 independent chains of 4 (full 128x128 matvec, one wave)
        v4f acc[8];
        #pragma unroll
        for (int T = 0; T < 8; ++T) {
            v4f a = {0.f, 0.f, 0.f, 0.f};
            a = __builtin_amdgcn_mfma_f32_16x16x32_bf16(Ef[T][0], B0, a, 0, 0, 0);
            a = __builtin_amdgcn_mfma_f32_16x16x32_bf16(Ef[T][1], B1, a, 0, 0, 0);
            a = __builtin_amdgcn_mfma_f32_16x16x32_bf16(Ef[T][2], B2, a, 0, 0, 0);
            a = __builtin_amdgcn_mfma_f32_16x16x32_bf16(Ef[T][3], B3, a, 0, 0, 0);
            acc[T] = a;
        }

        // epilogue over 8 lanes (col<2): col 0 -> tiles 0..3, col 1 -> tiles 4..7.
        // C layout: lane holds rows 4*quad+r of its tile (all cols identical).
        if (col < 2) {
            #pragma unroll
            for (int T = 0; T < 4; ++T) {
                float q0 = col ? acc[T + 4][0] : acc[T][0];
                float q1 = col ? acc[T + 4][1] : acc[T][1];
                float q2 = col ? acc[T + 4][2] : acc[T][2];
                float q3 = col ? acc[T + 4][3] : acc[T][3];
                const int row0 = 16 * (T + 4 * col) + tq;
                float4 e = *(const float4*)&es[row0];
                float s0, s1, s2, s3;
                if (phase == 2) {
                    s0 = q0 * (e.x * invv); s1 = q1 * (e.y * invv);
                    s2 = q2 * (e.z * invv); s3 = q3 * (e.w * invv);
                } else {
                    s0 = q0 * e.x; s1 = q1 * e.y; s2 = q2 * e.z; s3 = q3 * e.w;
                }
                // truncation-pack to bf16 (2 inst/pair; bias negligible vs threshold)
                unsigned lo = (__float_as_uint(s1) & 0xffff0000u) | (__float_as_uint(s0) >> 16);
                unsigned hi = (__float_as_uint(s3) & 0xffff0000u) | (__float_as_uint(s2) >> 16);
                *(uint2*)((unsigned short*)pbuf + row0) = make_uint2(lo, hi);
            }
        }
        // no barrier: next step's ds_read is ordered after these writes by lgkmcnt (same wave)
    };

    // ---------------- main loop ----------------
    for (int t0 = 0; t0 < L; t0 += GS) {
        const int buf = (t0 / GS) & 1;
        if (t0 + GS < L) stage(t0 + GS, buf ^ 1);   // loads in flight across the whole group
        const int ns = (L - t0 < GS) ? (L - t0) : GS;
        int s = 0;
        for (; s + 4 <= ns; s += 4) {               // literal phases (t0 is a multiple of 4)
            step(0, &xst[buf][s + 0][0]);
            step(1, &xst[buf][s + 1][0]);
            step(2, &xst[buf][s + 2][0]);
            step(3, &xst[buf][s + 3][0]);
        }
        for (; s < ns; ++s) step(s & 3, &xst[buf][s][0]);   // generic tail (L%4 != 0)
    }

    // ---------------- logZ = lsc2*ln2 + log(sum p_L * exp(trans[END,:])) ----------------
    float z = 0.f;
    #pragma unroll
    for (int r = 0; r < 2; ++r) {
        int rr = lane + 64 * r;
        z += bf2f(pbuf[rr]) * __expf(trans[END_T * RN + rr]);
    }
    #pragma unroll
    for (int off = 1; off < 64; off <<= 1) z += __shfl_xor(z, off, 64);
    if (lane == 0)
        out[b] = (float)lsc2 * 0.69314718055994531f + __logf(z) - goldv;
}

extern "C" void kernel_launch(void* const* d_in, const int* in_sizes, int n_in,
                              void* d_out, int out_size, void* d_ws, size_t ws_size,
                              hipStream_t stream) {
    const float* X     = (const float*)d_in[0];
    const int*   y     = (const int*)d_in[1];
    const float* trans = (const float*)d_in[2];
    float*       out   = (float*)d_out;

    const int B = out_size;            // 256
    const int L = in_sizes[1] / B;     // 1024

    crf_nll_kernel<<<dim3(B), dim3(64), 0, stream>>>(X, y, trans, out, L);
}